// Round 7
// baseline (1032.800 us; speedup 1.0000x reference)
//
#include <hip/hip_runtime.h>
#include <hip/hip_bf16.h>

// ---------------------------------------------------------------------------
// GIN0 (GINE x3 + BN + head) forward.
// R1: CSR + per-node register aggregation (no atomics in hot path).
// R3: node MLP GEMMs on MFMA via split-bf16 (hi+lo, 3-pass).
// R5: BN stats fused into GEMM2 epilogue; single prep kernel.
// R6: gathers read a bf16 copy of h (half gather bytes). Self-term fp32.
// R7: agg masked 8-edge loop (no scalar tail, 8 gathers in flight);
//     bn_apply vectorized float4/ushort4.
// ---------------------------------------------------------------------------

typedef __attribute__((ext_vector_type(8))) short short8;
typedef __attribute__((ext_vector_type(4))) float floatx4;
typedef __attribute__((ext_vector_type(2))) float float2v;

__device__ __forceinline__ float2v splat2(float s) {
    float2v v; v[0] = s; v[1] = s; return v;
}

__device__ __forceinline__ ushort f2bf_rne(float x) {
    unsigned u = __float_as_uint(x);
    unsigned r = (u + 0x7FFFu + ((u >> 16) & 1u)) >> 16;
    return (ushort)r;
}

__device__ __forceinline__ float bf2f(ushort u) {
    return __uint_as_float(((unsigned)u) << 16);
}

// ---------------- CSR build ----------------

__global__ __launch_bounds__(256) void hist_kernel(const int* __restrict__ dst,
                                                   int* __restrict__ deg, int E) {
    int i = blockIdx.x * blockDim.x + threadIdx.x;
    int stride = gridDim.x * blockDim.x;
    for (; i < E; i += stride) atomicAdd(&deg[dst[i]], 1);
}

__global__ __launch_bounds__(1024) void scan_kernel(const int* __restrict__ deg,
                                                    int* __restrict__ row_start, int N) {
    __shared__ int part[1024];
    int tid = threadIdx.x;
    int per = (N + 1023) / 1024;
    int start = tid * per;
    int end = min(start + per, N);
    int s = 0;
    for (int i = start; i < end; ++i) s += deg[i];
    part[tid] = s;
    __syncthreads();
    if (tid == 0) {
        int t = 0;
        for (int i = 0; i < 1024; ++i) {
            int v = part[i];
            part[i] = t;
            t += v;
        }
    }
    __syncthreads();
    int run = part[tid];
    for (int i = start; i < end; ++i) {
        row_start[i] = run;
        run += deg[i];
    }
    if (tid == 1023) row_start[N] = run;
}

__global__ __launch_bounds__(256) void scatter_kernel(
    const int* __restrict__ src, const int* __restrict__ dst,
    const int* __restrict__ row_start, int* __restrict__ cursor,
    int* __restrict__ csr_eid, int* __restrict__ csr_src, int E) {
    int i = blockIdx.x * blockDim.x + threadIdx.x;
    int stride = gridDim.x * blockDim.x;
    for (; i < E; i += stride) {
        int v = dst[i];
        int p = row_start[v] + atomicAdd(&cursor[v], 1);
        csr_eid[p] = i;
        csr_src[p] = src[i];
    }
}

// ---------------- Weight prep ----------------
__device__ __forceinline__ void wsplit(const float* W, ushort* Wth, ushort* Wtl,
                                       int K, int N, int t) {
    int k = t / N, n = t - k * N;
    float v = W[t];
    ushort hv = f2bf_rne(v);
    float hf = bf2f(hv);
    ushort lv = f2bf_rne(v - hf);
    Wth[(size_t)n * K + k] = hv;
    Wtl[(size_t)n * K + k] = lv;
}

__global__ __launch_bounds__(256) void prep_all(
    const float* W11, ushort* W11h, ushort* W11l,
    const float* W12, ushort* W12h, ushort* W12l,
    const float* W21, ushort* W21h, ushort* W21l,
    const float* W22, ushort* W22h, ushort* W22l,
    const float* W31, ushort* W31h, ushort* W31l,
    const float* W32, ushort* W32h, ushort* W32l) {
    int t = blockIdx.x * blockDim.x + threadIdx.x;
    const int s1 = 128 * 256, s2 = s1 + 256 * 256, s3 = s2 + 256 * 128;
    const int s4 = s3 + 128 * 128, s5 = s4 + 128 * 64, s6 = s5 + 64 * 64;
    if (t < s1) wsplit(W11, W11h, W11l, 128, 256, t);
    else if (t < s2) wsplit(W12, W12h, W12l, 256, 256, t - s1);
    else if (t < s3) wsplit(W21, W21h, W21l, 256, 128, t - s2);
    else if (t < s4) wsplit(W22, W22h, W22l, 128, 128, t - s3);
    else if (t < s5) wsplit(W31, W31h, W31l, 128, 64, t - s4);
    else if (t < s6) wsplit(W32, W32h, W32l, 64, 64, t - s5);
}

// ---------------- fp32 -> bf16 convert (layer-1 gather copy) --------------
__global__ __launch_bounds__(256) void f32_to_bf16(const float* __restrict__ in,
                                                   ushort* __restrict__ out, long n4) {
    long i = (long)blockIdx.x * blockDim.x + threadIdx.x;
    long stride = (long)gridDim.x * blockDim.x;
    for (; i < n4; i += stride) {
        float4 v = ((const float4*)in)[i];
        ushort4 o;
        o.x = f2bf_rne(v.x);
        o.y = f2bf_rne(v.y);
        o.z = f2bf_rne(v.z);
        o.w = f2bf_rne(v.w);
        ((ushort4*)out)[i] = o;
    }
}

// ---------------- Fused GINE aggregation ----------------
// One wave per node. Lane owns CPL = D/64 contiguous channels. 8 edges per
// iteration (wave-uniform full/masked split -- e0/e1 uniform across wave).
template <int D>
__global__ __launch_bounds__(256) void gine_agg_kernel(
    const float* __restrict__ h, const ushort* __restrict__ hb,
    const float* __restrict__ ea,
    const int* __restrict__ row_start, const int* __restrict__ csr_eid,
    const int* __restrict__ csr_src,
    const float* __restrict__ We, const float* __restrict__ be,
    ushort* __restrict__ uhi, ushort* __restrict__ ulo, int N) {
    constexpr int CPL = D / 64;  // channels per lane (2 or 4)
    constexpr int C2 = CPL / 2;  // float2 chunks
    const int lane = threadIdx.x & 63;
    const int ch0 = lane * CPL;

    float2v w[16][C2];
#pragma unroll
    for (int k = 0; k < 16; ++k)
#pragma unroll
        for (int c = 0; c < C2; ++c)
            w[k][c] = *(const float2v*)&We[k * D + ch0 + 2 * c];
    float2v bias[C2];
#pragma unroll
    for (int c = 0; c < C2; ++c) bias[c] = *(const float2v*)&be[ch0 + 2 * c];

    int v = blockIdx.x * 4 + (threadIdx.x >> 6);
    const int vstride = gridDim.x * 4;
    const float2v z2 = splat2(0.f);

    for (; v < N; v += vstride) {
        const int e0 = row_start[v];
        const int e1 = row_start[v + 1];
        float2v acc[C2];
#pragma unroll
        for (int c = 0; c < C2; ++c) acc[c] = z2;

        int i = e0;
        // ---- full 8-edge iterations (wave-uniform condition) ----
        for (; i + 8 <= e1; i += 8) {
            int myeid = csr_eid[i + (lane >> 3)];
            float2v eav = *(const float2v*)&ea[(size_t)myeid * 16 + (lane & 7) * 2];
            float2v hv[8][C2];
#pragma unroll
            for (int j = 0; j < 8; ++j) {
                int s = csr_src[i + j];
                if (CPL == 4) {
                    ushort4 r = *(const ushort4*)&hb[(size_t)s * D + ch0];
                    hv[j][0][0] = bf2f(r.x);
                    hv[j][0][1] = bf2f(r.y);
                    hv[j][C2 - 1][0] = bf2f(r.z);
                    hv[j][C2 - 1][1] = bf2f(r.w);
                } else {
                    ushort2 r = *(const ushort2*)&hb[(size_t)s * D + ch0];
                    hv[j][0][0] = bf2f(r.x);
                    hv[j][0][1] = bf2f(r.y);
                }
            }
#pragma unroll
            for (int j = 0; j < 8; ++j) {
                float wk[16];
#pragma unroll
                for (int k = 0; k < 16; ++k)
                    wk[k] = __int_as_float(__builtin_amdgcn_readlane(
                        __float_as_int(eav[k & 1]), j * 8 + (k >> 1)));
#pragma unroll
                for (int c = 0; c < C2; ++c) {
                    float2v p = bias[c];
#pragma unroll
                    for (int k = 0; k < 16; ++k)
                        p = __builtin_elementwise_fma(splat2(wk[k]), w[k][c], p);
                    float2v m = p + hv[j][c];
                    acc[c] += __builtin_elementwise_max(m, z2);
                }
            }
        }
        // ---- one masked iteration for the remainder (uniform per-j guard) ----
        if (i < e1) {
            int eclamp = e1 - 1;
            int myeid = csr_eid[min(i + (lane >> 3), eclamp)];
            float2v eav = *(const float2v*)&ea[(size_t)myeid * 16 + (lane & 7) * 2];
#pragma unroll
            for (int j = 0; j < 8; ++j) {
                if (i + j < e1) {
                    int s = csr_src[i + j];
                    float2v hv[C2];
                    if (CPL == 4) {
                        ushort4 r = *(const ushort4*)&hb[(size_t)s * D + ch0];
                        hv[0][0] = bf2f(r.x);
                        hv[0][1] = bf2f(r.y);
                        hv[C2 - 1][0] = bf2f(r.z);
                        hv[C2 - 1][1] = bf2f(r.w);
                    } else {
                        ushort2 r = *(const ushort2*)&hb[(size_t)s * D + ch0];
                        hv[0][0] = bf2f(r.x);
                        hv[0][1] = bf2f(r.y);
                    }
                    float wk[16];
#pragma unroll
                    for (int k = 0; k < 16; ++k)
                        wk[k] = __int_as_float(__builtin_amdgcn_readlane(
                            __float_as_int(eav[k & 1]), j * 8 + (k >> 1)));
#pragma unroll
                    for (int c = 0; c < C2; ++c) {
                        float2v p = bias[c];
#pragma unroll
                        for (int k = 0; k < 16; ++k)
                            p = __builtin_elementwise_fma(splat2(wk[k]), w[k][c], p);
                        float2v m = p + hv[c];
                        acc[c] += __builtin_elementwise_max(m, z2);
                    }
                }
            }
        }
        // ---- epilogue: u = h_v + acc, emitted as bf16 hi/lo ----
        ushort hi[CPL], lo[CPL];
#pragma unroll
        for (int c = 0; c < C2; ++c) {
            float2v sv = *(const float2v*)&h[(size_t)v * D + ch0 + 2 * c];
#pragma unroll
            for (int j = 0; j < 2; ++j) {
                float uv = sv[j] + acc[c][j];
                ushort hu = f2bf_rne(uv);
                ushort lu = f2bf_rne(uv - bf2f(hu));
                hi[2 * c + j] = hu;
                lo[2 * c + j] = lu;
            }
        }
        if (CPL == 4) {
            *(ushort4*)&uhi[(size_t)v * D + ch0] =
                make_ushort4(hi[0], hi[1], hi[CPL - 2], hi[CPL - 1]);
            *(ushort4*)&ulo[(size_t)v * D + ch0] =
                make_ushort4(lo[0], lo[1], lo[CPL - 2], lo[CPL - 1]);
        } else {
            *(ushort2*)&uhi[(size_t)v * D + ch0] = make_ushort2(hi[0], hi[1]);
            *(ushort2*)&ulo[(size_t)v * D + ch0] = make_ushort2(lo[0], lo[1]);
        }
    }
}

// ---------------- Split-bf16 MFMA GEMM (+ optional fused BN stats) ---------
template <int WRITE_BF16, int STATS>
__global__ __launch_bounds__(256) void gemm_mfma(
    const ushort* __restrict__ Ah, const ushort* __restrict__ Al,
    const ushort* __restrict__ Bh, const ushort* __restrict__ Bl,
    const float* __restrict__ bias,
    float* __restrict__ Cf, ushort* __restrict__ Chi, ushort* __restrict__ Clo,
    float* __restrict__ stats, int Nreal,
    int N, int K, int relu) {
    __shared__ ushort sA[2][128][72];
    __shared__ ushort sB[2][64][72];
    const int tid = threadIdx.x;
    const int wave = tid >> 6, lane = tid & 63;
    const int lrow = lane & 15, lquad = lane >> 4;
    const int bm = blockIdx.y * 128;
    const int bn = blockIdx.x * 64;

    floatx4 acc[2][4];
#pragma unroll
    for (int i = 0; i < 2; ++i)
#pragma unroll
        for (int j = 0; j < 4; ++j) acc[i][j] = (floatx4)0.f;

    for (int k0 = 0; k0 < K; k0 += 64) {
        for (int s = tid; s < 1024; s += 256) {
            int row = s >> 3, c8 = (s & 7) * 8;
            size_t g = (size_t)(bm + row) * K + k0 + c8;
            *(int4*)&sA[0][row][c8] = *(const int4*)&Ah[g];
            *(int4*)&sA[1][row][c8] = *(const int4*)&Al[g];
        }
        for (int s = tid; s < 512; s += 256) {
            int row = s >> 3, c8 = (s & 7) * 8;
            size_t g = (size_t)(bn + row) * K + k0 + c8;
            *(int4*)&sB[0][row][c8] = *(const int4*)&Bh[g];
            *(int4*)&sB[1][row][c8] = *(const int4*)&Bl[g];
        }
        __syncthreads();
        const int rb = wave * 32;
#pragma unroll
        for (int kk = 0; kk < 2; ++kk) {
            int ko = kk * 32 + lquad * 8;
            short8 ah[2], al[2], bh[4], bl[4];
#pragma unroll
            for (int i = 0; i < 2; ++i) {
                ah[i] = *(const short8*)&sA[0][rb + i * 16 + lrow][ko];
                al[i] = *(const short8*)&sA[1][rb + i * 16 + lrow][ko];
            }
#pragma unroll
            for (int j = 0; j < 4; ++j) {
                bh[j] = *(const short8*)&sB[0][j * 16 + lrow][ko];
                bl[j] = *(const short8*)&sB[1][j * 16 + lrow][ko];
            }
#pragma unroll
            for (int i = 0; i < 2; ++i)
#pragma unroll
                for (int j = 0; j < 4; ++j) {
                    acc[i][j] = __builtin_amdgcn_mfma_f32_16x16x32_bf16(
                        ah[i], bh[j], acc[i][j], 0, 0, 0);
                    acc[i][j] = __builtin_amdgcn_mfma_f32_16x16x32_bf16(
                        ah[i], bl[j], acc[i][j], 0, 0, 0);
                    acc[i][j] = __builtin_amdgcn_mfma_f32_16x16x32_bf16(
                        al[i], bh[j], acc[i][j], 0, 0, 0);
                }
        }
        __syncthreads();
    }
    float sj[4] = {0.f, 0.f, 0.f, 0.f};
    float qj[4] = {0.f, 0.f, 0.f, 0.f};
#pragma unroll
    for (int i = 0; i < 2; ++i)
#pragma unroll
        for (int j = 0; j < 4; ++j) {
            int gc = bn + j * 16 + lrow;
            float bv = bias[gc];
#pragma unroll
            for (int r = 0; r < 4; ++r) {
                int gr = bm + wave * 32 + i * 16 + lquad * 4 + r;
                float v = acc[i][j][r] + bv;
                if (relu) v = fmaxf(v, 0.f);
                if (STATS && gr < Nreal) {
                    sj[j] += v;
                    qj[j] = fmaf(v, v, qj[j]);
                }
                if (WRITE_BF16) {
                    ushort hv = f2bf_rne(v);
                    ushort lv = f2bf_rne(v - bf2f(hv));
                    Chi[(size_t)gr * N + gc] = hv;
                    Clo[(size_t)gr * N + gc] = lv;
                } else {
                    Cf[(size_t)gr * N + gc] = v;
                }
            }
        }
    if (STATS) {
#pragma unroll
        for (int j = 0; j < 4; ++j) {
            float s = sj[j], q = qj[j];
            s += __shfl_xor(s, 16);
            s += __shfl_xor(s, 32);
            q += __shfl_xor(q, 16);
            q += __shfl_xor(q, 32);
            if (lquad == 0) {
                int gc = bn + j * 16 + lrow;
                atomicAdd(&stats[gc], s);
                atomicAdd(&stats[N + gc], q);
            }
        }
    }
}

// ---------------- BatchNorm apply (vectorized, + bf16 copy) ----------------
__global__ __launch_bounds__(256) void bn_apply_kernel(
    const float* __restrict__ r, float* __restrict__ h,
    ushort* __restrict__ hbout,
    const float* __restrict__ sums,
    const float* __restrict__ g, const float* __restrict__ bt,
    int N, int D, int Dm1) {
    int idx = blockIdx.x * blockDim.x + threadIdx.x;
    int total4 = N * D / 4;
    int stride = gridDim.x * blockDim.x;
    float invN = 1.0f / (float)N;
    for (; idx < total4; idx += stride) {
        int c = (idx * 4) & Dm1;
        float4 s4 = *(const float4*)&sums[c];
        float4 q4 = *(const float4*)&sums[D + c];
        float4 g4 = *(const float4*)&g[c];
        float4 b4 = *(const float4*)&bt[c];
        float4 r4 = ((const float4*)r)[idx];
        float4 o;
        {
            float mu = s4.x * invN;
            float var = fmaf(-mu, mu, q4.x * invN);
            o.x = (r4.x - mu) * (rsqrtf(var + 1e-5f) * g4.x) + b4.x;
            mu = s4.y * invN;
            var = fmaf(-mu, mu, q4.y * invN);
            o.y = (r4.y - mu) * (rsqrtf(var + 1e-5f) * g4.y) + b4.y;
            mu = s4.z * invN;
            var = fmaf(-mu, mu, q4.z * invN);
            o.z = (r4.z - mu) * (rsqrtf(var + 1e-5f) * g4.z) + b4.z;
            mu = s4.w * invN;
            var = fmaf(-mu, mu, q4.w * invN);
            o.w = (r4.w - mu) * (rsqrtf(var + 1e-5f) * g4.w) + b4.w;
        }
        ((float4*)h)[idx] = o;
        if (hbout) {
            ushort4 ob;
            ob.x = f2bf_rne(o.x);
            ob.y = f2bf_rne(o.y);
            ob.z = f2bf_rne(o.z);
            ob.w = f2bf_rne(o.w);
            ((ushort4*)hbout)[idx] = ob;
        }
    }
}

// ---------------- Head ----------------
__global__ void head_kernel(const float* __restrict__ h, const int* __restrict__ n_nodes,
                            const float* __restrict__ Wf1, const float* __restrict__ bf1,
                            const float* __restrict__ Wf2, const float* __restrict__ bf2,
                            float* __restrict__ out, int G) {
    int g = blockIdx.x * blockDim.x + threadIdx.x;
    if (g >= G) return;
    int s = 0;
    for (int i = 0; i <= g; ++i) s += n_nodes[i];
    const float* m = &h[(size_t)(s - 1) * 64];
    float o = bf2[0];
#pragma unroll 4
    for (int j = 0; j < 16; ++j) {
        float acc = bf1[j];
        for (int k = 0; k < 64; ++k) acc = fmaf(m[k], Wf1[k * 16 + j], acc);
        acc = fmaxf(acc, 0.f);
        o = fmaf(acc, Wf2[j], o);
    }
    out[g] = o;
}

extern "C" void kernel_launch(void* const* d_in, const int* in_sizes, int n_in,
                              void* d_out, int out_size, void* d_ws, size_t ws_size,
                              hipStream_t stream) {
    const float* x = (const float*)d_in[0];
    const float* ea = (const float*)d_in[1];
    const int* eidx = (const int*)d_in[2];
    const int* n_nodes = (const int*)d_in[3];
    const float* We1 = (const float*)d_in[4];
    const float* be1 = (const float*)d_in[5];
    const float* W11 = (const float*)d_in[6];
    const float* b11 = (const float*)d_in[7];
    const float* W12 = (const float*)d_in[8];
    const float* b12 = (const float*)d_in[9];
    const float* g1 = (const float*)d_in[10];
    const float* bt1 = (const float*)d_in[11];
    const float* We2 = (const float*)d_in[12];
    const float* be2 = (const float*)d_in[13];
    const float* W21 = (const float*)d_in[14];
    const float* b21 = (const float*)d_in[15];
    const float* W22 = (const float*)d_in[16];
    const float* b22 = (const float*)d_in[17];
    const float* g2 = (const float*)d_in[18];
    const float* bt2 = (const float*)d_in[19];
    const float* We3 = (const float*)d_in[20];
    const float* be3 = (const float*)d_in[21];
    const float* W31 = (const float*)d_in[22];
    const float* b31 = (const float*)d_in[23];
    const float* W32 = (const float*)d_in[24];
    const float* b32 = (const float*)d_in[25];
    const float* g3 = (const float*)d_in[26];
    const float* bt3 = (const float*)d_in[27];
    const float* Wf1 = (const float*)d_in[28];
    const float* bf1 = (const float*)d_in[29];
    const float* Wf2 = (const float*)d_in[30];
    const float* bf2 = (const float*)d_in[31];

    const int N = in_sizes[0] / 128;  // 50000
    const int E = in_sizes[2] / 2;    // 800000
    const int G = in_sizes[3];        // 500
    const int Mp = ((N + 127) / 128) * 128;  // 50048
    const int* srcp = eidx;
    const int* dstp = eidx + E;

    float* H = (float*)d_ws;            // Mp x 256 fp32
    float* UR = H + (size_t)Mp * 256;   // Mp x 256: u(hi/lo bf16) / r(fp32)
    float* TT = UR + (size_t)Mp * 256;  // Mp x 256: t(hi/lo bf16) / hb(bf16)
    float* stats1 = TT + (size_t)Mp * 256;  // 512
    float* stats2 = stats1 + 512;           // 256
    float* stats3 = stats2 + 256;           // 128
    int* deg = (int*)(stats3 + 128);        // N
    int* cursor = deg + N;                  // N
    int* row_start = cursor + N;            // N+1
    int* csr_eid = row_start + N + 1;       // E
    int* csr_src = csr_eid + E;             // E
    size_t woff = (size_t)(csr_src + E - (int*)d_ws);
    woff = (woff + 3) & ~(size_t)3;
    ushort* wp = (ushort*)((int*)d_ws + woff);
    ushort* W11th = wp; wp += 128 * 256;
    ushort* W11tl = wp; wp += 128 * 256;
    ushort* W12th = wp; wp += 256 * 256;
    ushort* W12tl = wp; wp += 256 * 256;
    ushort* W21th = wp; wp += 256 * 128;
    ushort* W21tl = wp; wp += 256 * 128;
    ushort* W22th = wp; wp += 128 * 128;
    ushort* W22tl = wp; wp += 128 * 128;
    ushort* W31th = wp; wp += 128 * 64;
    ushort* W31tl = wp; wp += 128 * 64;
    ushort* W32th = wp; wp += 64 * 64;
    ushort* W32tl = wp; wp += 64 * 64;

    hipMemsetAsync(stats1, 0, 896 * sizeof(float) + (size_t)2 * N * sizeof(int), stream);

    const int prepTot = 128 * 256 + 256 * 256 + 256 * 128 + 128 * 128 + 128 * 64 + 64 * 64;
    prep_all<<<(prepTot + 255) / 256, 256, 0, stream>>>(
        W11, W11th, W11tl, W12, W12th, W12tl, W21, W21th, W21tl,
        W22, W22th, W22tl, W31, W31th, W31tl, W32, W32th, W32tl);

    hist_kernel<<<3125, 256, 0, stream>>>(dstp, deg, E);
    scan_kernel<<<1, 1024, 0, stream>>>(deg, row_start, N);
    scatter_kernel<<<3125, 256, 0, stream>>>(srcp, dstp, row_start, cursor,
                                             csr_eid, csr_src, E);

    const int aggBlocks = (N + 3) / 4;
    const int gy = Mp / 128;
    float* R = UR;
    ushort* HB = (ushort*)TT;  // bf16 gather copy lives in the (dead) TT region

    // ---------------- Layer 1: 128 -> 256 -> 256 ----------------
    {
        ushort* Uhi = (ushort*)UR; ushort* Ulo = Uhi + (size_t)Mp * 128;
        ushort* Thi = (ushort*)TT; ushort* Tlo = Thi + (size_t)Mp * 256;
        f32_to_bf16<<<2048, 256, 0, stream>>>(x, HB, (long)N * 128 / 4);
        gine_agg_kernel<128><<<aggBlocks, 256, 0, stream>>>(
            x, HB, ea, row_start, csr_eid, csr_src, We1, be1, Uhi, Ulo, N);
        gemm_mfma<1, 0><<<dim3(4, gy), 256, 0, stream>>>(
            Uhi, Ulo, W11th, W11tl, b11, nullptr, Thi, Tlo, nullptr, 0, 256, 128, 1);
        gemm_mfma<0, 1><<<dim3(4, gy), 256, 0, stream>>>(
            Thi, Tlo, W12th, W12tl, b12, R, nullptr, nullptr, stats1, N, 256, 256, 1);
        bn_apply_kernel<<<2048, 256, 0, stream>>>(R, H, HB, stats1, g1, bt1, N, 256, 255);
    }

    // ---------------- Layer 2: 256 -> 128 -> 128 ----------------
    {
        ushort* Uhi = (ushort*)UR; ushort* Ulo = Uhi + (size_t)Mp * 256;
        ushort* Thi = (ushort*)TT; ushort* Tlo = Thi + (size_t)Mp * 128;
        gine_agg_kernel<256><<<aggBlocks, 256, 0, stream>>>(
            H, HB, ea, row_start, csr_eid, csr_src, We2, be2, Uhi, Ulo, N);
        gemm_mfma<1, 0><<<dim3(2, gy), 256, 0, stream>>>(
            Uhi, Ulo, W21th, W21tl, b21, nullptr, Thi, Tlo, nullptr, 0, 128, 256, 1);
        gemm_mfma<0, 1><<<dim3(2, gy), 256, 0, stream>>>(
            Thi, Tlo, W22th, W22tl, b22, R, nullptr, nullptr, stats2, N, 128, 128, 1);
        bn_apply_kernel<<<2048, 256, 0, stream>>>(R, H, HB, stats2, g2, bt2, N, 128, 127);
    }

    // ---------------- Layer 3: 128 -> 64 -> 64 ----------------
    {
        ushort* Uhi = (ushort*)UR; ushort* Ulo = Uhi + (size_t)Mp * 128;
        ushort* Thi = (ushort*)TT; ushort* Tlo = Thi + (size_t)Mp * 64;
        gine_agg_kernel<128><<<aggBlocks, 256, 0, stream>>>(
            H, HB, ea, row_start, csr_eid, csr_src, We3, be3, Uhi, Ulo, N);
        gemm_mfma<1, 0><<<dim3(1, gy), 256, 0, stream>>>(
            Uhi, Ulo, W31th, W31tl, b31, nullptr, Thi, Tlo, nullptr, 0, 64, 128, 1);
        gemm_mfma<0, 1><<<dim3(1, gy), 256, 0, stream>>>(
            Thi, Tlo, W32th, W32tl, b32, R, nullptr, nullptr, stats3, N, 64, 64, 1);
        bn_apply_kernel<<<2048, 256, 0, stream>>>(R, H, nullptr, stats3, g3, bt3, N, 64, 63);
    }

    // ---------------- Head ----------------
    head_kernel<<<(G + 255) / 256, 256, 0, stream>>>(H, n_nodes, Wf1, bf1, Wf2, bf2,
                                                     (float*)d_out, G);
}

// Round 8
// 997.173 us; speedup vs baseline: 1.0357x; 1.0357x over previous
//
#include <hip/hip_runtime.h>
#include <hip/hip_bf16.h>

// ---------------------------------------------------------------------------
// GIN0 (GINE x3 + BN + head) forward.
// R1: CSR + per-node register aggregation (no atomics in hot path).
// R3: node MLP GEMMs on MFMA via split-bf16 (hi+lo, 3-pass).
// R5: BN stats fused into GEMM2 epilogue; single prep kernel.
// R6: gathers read a bf16 copy of h; self-term fp32; 4-edge unroll.
// R8: D=256 agg uses 2 waves/node (128 ch each) so We fits the compiler's
//     64-VGPR cap (w=32 regs resident; R6's D=256 re-fetched We per edge).
//     CSR stored interleaved int2 (1 scattered store, 1 load for eid+src).
// ---------------------------------------------------------------------------

typedef __attribute__((ext_vector_type(8))) short short8;
typedef __attribute__((ext_vector_type(4))) float floatx4;
typedef __attribute__((ext_vector_type(2))) float float2v;

__device__ __forceinline__ float2v splat2(float s) {
    float2v v; v[0] = s; v[1] = s; return v;
}

__device__ __forceinline__ ushort f2bf_rne(float x) {
    unsigned u = __float_as_uint(x);
    unsigned r = (u + 0x7FFFu + ((u >> 16) & 1u)) >> 16;
    return (ushort)r;
}

__device__ __forceinline__ float bf2f(ushort u) {
    return __uint_as_float(((unsigned)u) << 16);
}

// ---------------- CSR build ----------------

__global__ __launch_bounds__(256) void hist_kernel(const int* __restrict__ dst,
                                                   int* __restrict__ deg, int E) {
    int i = blockIdx.x * blockDim.x + threadIdx.x;
    int stride = gridDim.x * blockDim.x;
    for (; i < E; i += stride) atomicAdd(&deg[dst[i]], 1);
}

__global__ __launch_bounds__(1024) void scan_kernel(const int* __restrict__ deg,
                                                    int* __restrict__ row_start, int N) {
    __shared__ int part[1024];
    int tid = threadIdx.x;
    int per = (N + 1023) / 1024;
    int start = tid * per;
    int end = min(start + per, N);
    int s = 0;
    for (int i = start; i < end; ++i) s += deg[i];
    part[tid] = s;
    __syncthreads();
    if (tid == 0) {
        int t = 0;
        for (int i = 0; i < 1024; ++i) {
            int v = part[i];
            part[i] = t;
            t += v;
        }
    }
    __syncthreads();
    int run = part[tid];
    for (int i = start; i < end; ++i) {
        row_start[i] = run;
        run += deg[i];
    }
    if (tid == 1023) row_start[N] = run;
}

__global__ __launch_bounds__(256) void scatter_kernel(
    const int* __restrict__ src, const int* __restrict__ dst,
    const int* __restrict__ row_start, int* __restrict__ cursor,
    int2* __restrict__ csr, int E) {
    int i = blockIdx.x * blockDim.x + threadIdx.x;
    int stride = gridDim.x * blockDim.x;
    for (; i < E; i += stride) {
        int v = dst[i];
        int p = row_start[v] + atomicAdd(&cursor[v], 1);
        csr[p] = make_int2(i, src[i]);
    }
}

// ---------------- Weight prep ----------------
__device__ __forceinline__ void wsplit(const float* W, ushort* Wth, ushort* Wtl,
                                       int K, int N, int t) {
    int k = t / N, n = t - k * N;
    float v = W[t];
    ushort hv = f2bf_rne(v);
    float hf = bf2f(hv);
    ushort lv = f2bf_rne(v - hf);
    Wth[(size_t)n * K + k] = hv;
    Wtl[(size_t)n * K + k] = lv;
}

__global__ __launch_bounds__(256) void prep_all(
    const float* W11, ushort* W11h, ushort* W11l,
    const float* W12, ushort* W12h, ushort* W12l,
    const float* W21, ushort* W21h, ushort* W21l,
    const float* W22, ushort* W22h, ushort* W22l,
    const float* W31, ushort* W31h, ushort* W31l,
    const float* W32, ushort* W32h, ushort* W32l) {
    int t = blockIdx.x * blockDim.x + threadIdx.x;
    const int s1 = 128 * 256, s2 = s1 + 256 * 256, s3 = s2 + 256 * 128;
    const int s4 = s3 + 128 * 128, s5 = s4 + 128 * 64, s6 = s5 + 64 * 64;
    if (t < s1) wsplit(W11, W11h, W11l, 128, 256, t);
    else if (t < s2) wsplit(W12, W12h, W12l, 256, 256, t - s1);
    else if (t < s3) wsplit(W21, W21h, W21l, 256, 128, t - s2);
    else if (t < s4) wsplit(W22, W22h, W22l, 128, 128, t - s3);
    else if (t < s5) wsplit(W31, W31h, W31l, 128, 64, t - s4);
    else if (t < s6) wsplit(W32, W32h, W32l, 64, 64, t - s5);
}

// ---------------- fp32 -> bf16 convert (layer-1 gather copy) --------------
__global__ __launch_bounds__(256) void f32_to_bf16(const float* __restrict__ in,
                                                   ushort* __restrict__ out, long n4) {
    long i = (long)blockIdx.x * blockDim.x + threadIdx.x;
    long stride = (long)gridDim.x * blockDim.x;
    for (; i < n4; i += stride) {
        float4 v = ((const float4*)in)[i];
        ushort4 o;
        o.x = f2bf_rne(v.x);
        o.y = f2bf_rne(v.y);
        o.z = f2bf_rne(v.z);
        o.w = f2bf_rne(v.w);
        ((ushort4*)out)[i] = o;
    }
}

// ---------------- Fused GINE aggregation ----------------
// WPN waves per node, each owning 128 channels (2 per lane) -> We slice fits
// the 64-VGPR budget (32 regs) and stays resident. 4-edge unroll + scalar
// tail (R6 structure). CSR interleaved int2 {eid, src}.
template <int D, int WPN>
__global__ __launch_bounds__(256) void gine_agg_kernel(
    const float* __restrict__ h, const ushort* __restrict__ hb,
    const float* __restrict__ ea,
    const int* __restrict__ row_start, const int2* __restrict__ csr,
    const float* __restrict__ We, const float* __restrict__ be,
    ushort* __restrict__ uhi, ushort* __restrict__ ulo, int N) {
    constexpr int NPB = 4 / WPN;  // nodes per 256-thread block
    const int lane = threadIdx.x & 63;
    const int wid = threadIdx.x >> 6;
    const int ch0 = (wid % WPN) * 128 + lane * 2;

    float2v w[16];
#pragma unroll
    for (int k = 0; k < 16; ++k) w[k] = *(const float2v*)&We[k * D + ch0];
    const float2v bias = *(const float2v*)&be[ch0];

    int v = blockIdx.x * NPB + wid / WPN;
    const int vstride = gridDim.x * NPB;
    const float2v z2 = splat2(0.f);

    for (; v < N; v += vstride) {
        const int e0 = row_start[v];
        const int e1 = row_start[v + 1];
        float2v acc = z2;

        int i = e0;
        for (; i + 4 <= e1; i += 4) {
            int2 c2 = csr[i + (lane >> 4)];
            float eav = ea[(size_t)c2.x * 16 + (lane & 15)];
            int s0 = __builtin_amdgcn_readlane(c2.y, 0);
            int s1 = __builtin_amdgcn_readlane(c2.y, 16);
            int s2 = __builtin_amdgcn_readlane(c2.y, 32);
            int s3 = __builtin_amdgcn_readlane(c2.y, 48);
            ushort2 r0 = *(const ushort2*)&hb[(size_t)s0 * D + ch0];
            ushort2 r1 = *(const ushort2*)&hb[(size_t)s1 * D + ch0];
            ushort2 r2 = *(const ushort2*)&hb[(size_t)s2 * D + ch0];
            ushort2 r3 = *(const ushort2*)&hb[(size_t)s3 * D + ch0];
            float2v hv[4];
            hv[0][0] = bf2f(r0.x); hv[0][1] = bf2f(r0.y);
            hv[1][0] = bf2f(r1.x); hv[1][1] = bf2f(r1.y);
            hv[2][0] = bf2f(r2.x); hv[2][1] = bf2f(r2.y);
            hv[3][0] = bf2f(r3.x); hv[3][1] = bf2f(r3.y);
#pragma unroll
            for (int e = 0; e < 4; ++e) {
                float wk[16];
#pragma unroll
                for (int k = 0; k < 16; ++k)
                    wk[k] = __int_as_float(
                        __builtin_amdgcn_readlane(__float_as_int(eav), e * 16 + k));
                float2v p = bias;
#pragma unroll
                for (int k = 0; k < 16; ++k)
                    p = __builtin_elementwise_fma(splat2(wk[k]), w[k], p);
                float2v m = p + hv[e];
                acc += __builtin_elementwise_max(m, z2);
            }
        }
        for (; i < e1; ++i) {  // tail (<=3 edges)
            int2 ce = csr[i];
            float eav = (lane < 16) ? ea[(size_t)ce.x * 16 + lane] : 0.f;
            ushort2 r = *(const ushort2*)&hb[(size_t)ce.y * D + ch0];
            float wk[16];
#pragma unroll
            for (int k = 0; k < 16; ++k)
                wk[k] = __int_as_float(
                    __builtin_amdgcn_readlane(__float_as_int(eav), k));
            float2v p = bias;
#pragma unroll
            for (int k = 0; k < 16; ++k)
                p = __builtin_elementwise_fma(splat2(wk[k]), w[k], p);
            float2v hv;
            hv[0] = bf2f(r.x);
            hv[1] = bf2f(r.y);
            float2v m = p + hv;
            acc += __builtin_elementwise_max(m, z2);
        }
        // epilogue: u = h_v + acc -> bf16 hi/lo
        float2v sv = *(const float2v*)&h[(size_t)v * D + ch0];
        float u0 = sv[0] + acc[0];
        float u1 = sv[1] + acc[1];
        ushort h0 = f2bf_rne(u0);
        ushort h1 = f2bf_rne(u1);
        ushort l0 = f2bf_rne(u0 - bf2f(h0));
        ushort l1 = f2bf_rne(u1 - bf2f(h1));
        *(ushort2*)&uhi[(size_t)v * D + ch0] = make_ushort2(h0, h1);
        *(ushort2*)&ulo[(size_t)v * D + ch0] = make_ushort2(l0, l1);
    }
}

// ---------------- Split-bf16 MFMA GEMM (+ optional fused BN stats) ---------
template <int WRITE_BF16, int STATS>
__global__ __launch_bounds__(256) void gemm_mfma(
    const ushort* __restrict__ Ah, const ushort* __restrict__ Al,
    const ushort* __restrict__ Bh, const ushort* __restrict__ Bl,
    const float* __restrict__ bias,
    float* __restrict__ Cf, ushort* __restrict__ Chi, ushort* __restrict__ Clo,
    float* __restrict__ stats, int Nreal,
    int N, int K, int relu) {
    __shared__ ushort sA[2][128][72];
    __shared__ ushort sB[2][64][72];
    const int tid = threadIdx.x;
    const int wave = tid >> 6, lane = tid & 63;
    const int lrow = lane & 15, lquad = lane >> 4;
    const int bm = blockIdx.y * 128;
    const int bn = blockIdx.x * 64;

    floatx4 acc[2][4];
#pragma unroll
    for (int i = 0; i < 2; ++i)
#pragma unroll
        for (int j = 0; j < 4; ++j) acc[i][j] = (floatx4)0.f;

    for (int k0 = 0; k0 < K; k0 += 64) {
        for (int s = tid; s < 1024; s += 256) {
            int row = s >> 3, c8 = (s & 7) * 8;
            size_t g = (size_t)(bm + row) * K + k0 + c8;
            *(int4*)&sA[0][row][c8] = *(const int4*)&Ah[g];
            *(int4*)&sA[1][row][c8] = *(const int4*)&Al[g];
        }
        for (int s = tid; s < 512; s += 256) {
            int row = s >> 3, c8 = (s & 7) * 8;
            size_t g = (size_t)(bn + row) * K + k0 + c8;
            *(int4*)&sB[0][row][c8] = *(const int4*)&Bh[g];
            *(int4*)&sB[1][row][c8] = *(const int4*)&Bl[g];
        }
        __syncthreads();
        const int rb = wave * 32;
#pragma unroll
        for (int kk = 0; kk < 2; ++kk) {
            int ko = kk * 32 + lquad * 8;
            short8 ah[2], al[2], bh[4], bl[4];
#pragma unroll
            for (int i = 0; i < 2; ++i) {
                ah[i] = *(const short8*)&sA[0][rb + i * 16 + lrow][ko];
                al[i] = *(const short8*)&sA[1][rb + i * 16 + lrow][ko];
            }
#pragma unroll
            for (int j = 0; j < 4; ++j) {
                bh[j] = *(const short8*)&sB[0][j * 16 + lrow][ko];
                bl[j] = *(const short8*)&sB[1][j * 16 + lrow][ko];
            }
#pragma unroll
            for (int i = 0; i < 2; ++i)
#pragma unroll
                for (int j = 0; j < 4; ++j) {
                    acc[i][j] = __builtin_amdgcn_mfma_f32_16x16x32_bf16(
                        ah[i], bh[j], acc[i][j], 0, 0, 0);
                    acc[i][j] = __builtin_amdgcn_mfma_f32_16x16x32_bf16(
                        ah[i], bl[j], acc[i][j], 0, 0, 0);
                    acc[i][j] = __builtin_amdgcn_mfma_f32_16x16x32_bf16(
                        al[i], bh[j], acc[i][j], 0, 0, 0);
                }
        }
        __syncthreads();
    }
    float sj[4] = {0.f, 0.f, 0.f, 0.f};
    float qj[4] = {0.f, 0.f, 0.f, 0.f};
#pragma unroll
    for (int i = 0; i < 2; ++i)
#pragma unroll
        for (int j = 0; j < 4; ++j) {
            int gc = bn + j * 16 + lrow;
            float bv = bias[gc];
#pragma unroll
            for (int r = 0; r < 4; ++r) {
                int gr = bm + wave * 32 + i * 16 + lquad * 4 + r;
                float v = acc[i][j][r] + bv;
                if (relu) v = fmaxf(v, 0.f);
                if (STATS && gr < Nreal) {
                    sj[j] += v;
                    qj[j] = fmaf(v, v, qj[j]);
                }
                if (WRITE_BF16) {
                    ushort hv = f2bf_rne(v);
                    ushort lv = f2bf_rne(v - bf2f(hv));
                    Chi[(size_t)gr * N + gc] = hv;
                    Clo[(size_t)gr * N + gc] = lv;
                } else {
                    Cf[(size_t)gr * N + gc] = v;
                }
            }
        }
    if (STATS) {
#pragma unroll
        for (int j = 0; j < 4; ++j) {
            float s = sj[j], q = qj[j];
            s += __shfl_xor(s, 16);
            s += __shfl_xor(s, 32);
            q += __shfl_xor(q, 16);
            q += __shfl_xor(q, 32);
            if (lquad == 0) {
                int gc = bn + j * 16 + lrow;
                atomicAdd(&stats[gc], s);
                atomicAdd(&stats[N + gc], q);
            }
        }
    }
}

// ---------------- BatchNorm apply (vectorized, + bf16 copy) ----------------
__global__ __launch_bounds__(256) void bn_apply_kernel(
    const float* __restrict__ r, float* __restrict__ h,
    ushort* __restrict__ hbout,
    const float* __restrict__ sums,
    const float* __restrict__ g, const float* __restrict__ bt,
    int N, int D, int Dm1) {
    int idx = blockIdx.x * blockDim.x + threadIdx.x;
    int total4 = N * D / 4;
    int stride = gridDim.x * blockDim.x;
    float invN = 1.0f / (float)N;
    for (; idx < total4; idx += stride) {
        int c = (idx * 4) & Dm1;
        float4 s4 = *(const float4*)&sums[c];
        float4 q4 = *(const float4*)&sums[D + c];
        float4 g4 = *(const float4*)&g[c];
        float4 b4 = *(const float4*)&bt[c];
        float4 r4 = ((const float4*)r)[idx];
        float4 o;
        {
            float mu = s4.x * invN;
            float var = fmaf(-mu, mu, q4.x * invN);
            o.x = (r4.x - mu) * (rsqrtf(var + 1e-5f) * g4.x) + b4.x;
            mu = s4.y * invN;
            var = fmaf(-mu, mu, q4.y * invN);
            o.y = (r4.y - mu) * (rsqrtf(var + 1e-5f) * g4.y) + b4.y;
            mu = s4.z * invN;
            var = fmaf(-mu, mu, q4.z * invN);
            o.z = (r4.z - mu) * (rsqrtf(var + 1e-5f) * g4.z) + b4.z;
            mu = s4.w * invN;
            var = fmaf(-mu, mu, q4.w * invN);
            o.w = (r4.w - mu) * (rsqrtf(var + 1e-5f) * g4.w) + b4.w;
        }
        ((float4*)h)[idx] = o;
        if (hbout) {
            ushort4 ob;
            ob.x = f2bf_rne(o.x);
            ob.y = f2bf_rne(o.y);
            ob.z = f2bf_rne(o.z);
            ob.w = f2bf_rne(o.w);
            ((ushort4*)hbout)[idx] = ob;
        }
    }
}

// ---------------- Head ----------------
__global__ void head_kernel(const float* __restrict__ h, const int* __restrict__ n_nodes,
                            const float* __restrict__ Wf1, const float* __restrict__ bf1,
                            const float* __restrict__ Wf2, const float* __restrict__ bf2,
                            float* __restrict__ out, int G) {
    int g = blockIdx.x * blockDim.x + threadIdx.x;
    if (g >= G) return;
    int s = 0;
    for (int i = 0; i <= g; ++i) s += n_nodes[i];
    const float* m = &h[(size_t)(s - 1) * 64];
    float o = bf2[0];
#pragma unroll 4
    for (int j = 0; j < 16; ++j) {
        float acc = bf1[j];
        for (int k = 0; k < 64; ++k) acc = fmaf(m[k], Wf1[k * 16 + j], acc);
        acc = fmaxf(acc, 0.f);
        o = fmaf(acc, Wf2[j], o);
    }
    out[g] = o;
}

extern "C" void kernel_launch(void* const* d_in, const int* in_sizes, int n_in,
                              void* d_out, int out_size, void* d_ws, size_t ws_size,
                              hipStream_t stream) {
    const float* x = (const float*)d_in[0];
    const float* ea = (const float*)d_in[1];
    const int* eidx = (const int*)d_in[2];
    const int* n_nodes = (const int*)d_in[3];
    const float* We1 = (const float*)d_in[4];
    const float* be1 = (const float*)d_in[5];
    const float* W11 = (const float*)d_in[6];
    const float* b11 = (const float*)d_in[7];
    const float* W12 = (const float*)d_in[8];
    const float* b12 = (const float*)d_in[9];
    const float* g1 = (const float*)d_in[10];
    const float* bt1 = (const float*)d_in[11];
    const float* We2 = (const float*)d_in[12];
    const float* be2 = (const float*)d_in[13];
    const float* W21 = (const float*)d_in[14];
    const float* b21 = (const float*)d_in[15];
    const float* W22 = (const float*)d_in[16];
    const float* b22 = (const float*)d_in[17];
    const float* g2 = (const float*)d_in[18];
    const float* bt2 = (const float*)d_in[19];
    const float* We3 = (const float*)d_in[20];
    const float* be3 = (const float*)d_in[21];
    const float* W31 = (const float*)d_in[22];
    const float* b31 = (const float*)d_in[23];
    const float* W32 = (const float*)d_in[24];
    const float* b32 = (const float*)d_in[25];
    const float* g3 = (const float*)d_in[26];
    const float* bt3 = (const float*)d_in[27];
    const float* Wf1 = (const float*)d_in[28];
    const float* bf1 = (const float*)d_in[29];
    const float* Wf2 = (const float*)d_in[30];
    const float* bf2 = (const float*)d_in[31];

    const int N = in_sizes[0] / 128;  // 50000
    const int E = in_sizes[2] / 2;    // 800000
    const int G = in_sizes[3];        // 500
    const int Mp = ((N + 127) / 128) * 128;  // 50048
    const int* srcp = eidx;
    const int* dstp = eidx + E;

    float* H = (float*)d_ws;            // Mp x 256 fp32
    float* UR = H + (size_t)Mp * 256;   // Mp x 256: u(hi/lo bf16) / r(fp32)
    float* TT = UR + (size_t)Mp * 256;  // Mp x 256: t(hi/lo bf16) / hb(bf16)
    float* stats1 = TT + (size_t)Mp * 256;  // 512
    float* stats2 = stats1 + 512;           // 256
    float* stats3 = stats2 + 256;           // 128
    int* deg = (int*)(stats3 + 128);        // N
    int* cursor = deg + N;                  // N
    int* row_start = cursor + N;            // N+1 (+1 pad for int2 align)
    int2* csr = (int2*)(row_start + N + 2); // E int2
    size_t woff = (size_t)((int*)(csr + E) - (int*)d_ws);
    woff = (woff + 3) & ~(size_t)3;
    ushort* wp = (ushort*)((int*)d_ws + woff);
    ushort* W11th = wp; wp += 128 * 256;
    ushort* W11tl = wp; wp += 128 * 256;
    ushort* W12th = wp; wp += 256 * 256;
    ushort* W12tl = wp; wp += 256 * 256;
    ushort* W21th = wp; wp += 256 * 128;
    ushort* W21tl = wp; wp += 256 * 128;
    ushort* W22th = wp; wp += 128 * 128;
    ushort* W22tl = wp; wp += 128 * 128;
    ushort* W31th = wp; wp += 128 * 64;
    ushort* W31tl = wp; wp += 128 * 64;
    ushort* W32th = wp; wp += 64 * 64;
    ushort* W32tl = wp; wp += 64 * 64;

    hipMemsetAsync(stats1, 0, 896 * sizeof(float) + (size_t)2 * N * sizeof(int), stream);

    const int prepTot = 128 * 256 + 256 * 256 + 256 * 128 + 128 * 128 + 128 * 64 + 64 * 64;
    prep_all<<<(prepTot + 255) / 256, 256, 0, stream>>>(
        W11, W11th, W11tl, W12, W12th, W12tl, W21, W21th, W21tl,
        W22, W22th, W22tl, W31, W31th, W31tl, W32, W32th, W32tl);

    hist_kernel<<<3125, 256, 0, stream>>>(dstp, deg, E);
    scan_kernel<<<1, 1024, 0, stream>>>(deg, row_start, N);
    scatter_kernel<<<3125, 256, 0, stream>>>(srcp, dstp, row_start, cursor, csr, E);

    const int gy = Mp / 128;
    float* R = UR;
    ushort* HB = (ushort*)TT;  // bf16 gather copy lives in the (dead) TT region

    // ---------------- Layer 1: 128 -> 256 -> 256 ----------------
    {
        ushort* Uhi = (ushort*)UR; ushort* Ulo = Uhi + (size_t)Mp * 128;
        ushort* Thi = (ushort*)TT; ushort* Tlo = Thi + (size_t)Mp * 256;
        f32_to_bf16<<<2048, 256, 0, stream>>>(x, HB, (long)N * 128 / 4);
        gine_agg_kernel<128, 1><<<(N + 3) / 4, 256, 0, stream>>>(
            x, HB, ea, row_start, csr, We1, be1, Uhi, Ulo, N);
        gemm_mfma<1, 0><<<dim3(4, gy), 256, 0, stream>>>(
            Uhi, Ulo, W11th, W11tl, b11, nullptr, Thi, Tlo, nullptr, 0, 256, 128, 1);
        gemm_mfma<0, 1><<<dim3(4, gy), 256, 0, stream>>>(
            Thi, Tlo, W12th, W12tl, b12, R, nullptr, nullptr, stats1, N, 256, 256, 1);
        bn_apply_kernel<<<2048, 256, 0, stream>>>(R, H, HB, stats1, g1, bt1, N, 256, 255);
    }

    // ---------------- Layer 2: 256 -> 128 -> 128 ----------------
    {
        ushort* Uhi = (ushort*)UR; ushort* Ulo = Uhi + (size_t)Mp * 256;
        ushort* Thi = (ushort*)TT; ushort* Tlo = Thi + (size_t)Mp * 128;
        gine_agg_kernel<256, 2><<<(N + 1) / 2, 256, 0, stream>>>(
            H, HB, ea, row_start, csr, We2, be2, Uhi, Ulo, N);
        gemm_mfma<1, 0><<<dim3(2, gy), 256, 0, stream>>>(
            Uhi, Ulo, W21th, W21tl, b21, nullptr, Thi, Tlo, nullptr, 0, 128, 256, 1);
        gemm_mfma<0, 1><<<dim3(2, gy), 256, 0, stream>>>(
            Thi, Tlo, W22th, W22tl, b22, R, nullptr, nullptr, stats2, N, 128, 128, 1);
        bn_apply_kernel<<<2048, 256, 0, stream>>>(R, H, HB, stats2, g2, bt2, N, 128, 127);
    }

    // ---------------- Layer 3: 128 -> 64 -> 64 ----------------
    {
        ushort* Uhi = (ushort*)UR; ushort* Ulo = Uhi + (size_t)Mp * 128;
        ushort* Thi = (ushort*)TT; ushort* Tlo = Thi + (size_t)Mp * 64;
        gine_agg_kernel<128, 1><<<(N + 3) / 4, 256, 0, stream>>>(
            H, HB, ea, row_start, csr, We3, be3, Uhi, Ulo, N);
        gemm_mfma<1, 0><<<dim3(1, gy), 256, 0, stream>>>(
            Uhi, Ulo, W31th, W31tl, b31, nullptr, Thi, Tlo, nullptr, 0, 64, 128, 1);
        gemm_mfma<0, 1><<<dim3(1, gy), 256, 0, stream>>>(
            Thi, Tlo, W32th, W32tl, b32, R, nullptr, nullptr, stats3, N, 64, 64, 1);
        bn_apply_kernel<<<2048, 256, 0, stream>>>(R, H, nullptr, stats3, g3, bt3, N, 64, 63);
    }

    // ---------------- Head ----------------
    head_kernel<<<(G + 255) / 256, 256, 0, stream>>>(H, n_nodes, Wf1, bf1, Wf2, bf2,
                                                     (float*)d_out, G);
}

// Round 9
// 994.106 us; speedup vs baseline: 1.0389x; 1.0031x over previous
//
#include <hip/hip_runtime.h>
#include <hip/hip_bf16.h>

// ---------------------------------------------------------------------------
// GIN0 (GINE x3 + BN + head) forward.
// R1: CSR + per-node register aggregation (no atomics in hot path).
// R3: node MLP GEMMs on MFMA via split-bf16 (hi+lo, 3-pass).
// R5: BN stats fused into GEMM2 epilogue; single prep kernel.
// R6: gathers read a bf16 copy of h; self-term fp32.
// R8: WPN waves/node so We slice stays VGPR-resident; interleaved int2 CSR.
// R9: edge features via uniform (SGPR-address) loads instead of 16 readlanes
//     per edge per wave -- eid/src extracted to SGPRs (2 readlanes), ea row
//     loaded as 4 uniform float4 (s_load/broadcast). Halves agg VALU.
// ---------------------------------------------------------------------------

typedef __attribute__((ext_vector_type(8))) short short8;
typedef __attribute__((ext_vector_type(4))) float floatx4;
typedef __attribute__((ext_vector_type(2))) float float2v;

__device__ __forceinline__ float2v splat2(float s) {
    float2v v; v[0] = s; v[1] = s; return v;
}

__device__ __forceinline__ float2v fma2(float s, float2v w, float2v p) {
    return __builtin_elementwise_fma(splat2(s), w, p);
}

__device__ __forceinline__ ushort f2bf_rne(float x) {
    unsigned u = __float_as_uint(x);
    unsigned r = (u + 0x7FFFu + ((u >> 16) & 1u)) >> 16;
    return (ushort)r;
}

__device__ __forceinline__ float bf2f(ushort u) {
    return __uint_as_float(((unsigned)u) << 16);
}

// ---------------- CSR build ----------------

__global__ __launch_bounds__(256) void hist_kernel(const int* __restrict__ dst,
                                                   int* __restrict__ deg, int E) {
    int i = blockIdx.x * blockDim.x + threadIdx.x;
    int stride = gridDim.x * blockDim.x;
    for (; i < E; i += stride) atomicAdd(&deg[dst[i]], 1);
}

__global__ __launch_bounds__(1024) void scan_kernel(const int* __restrict__ deg,
                                                    int* __restrict__ row_start, int N) {
    __shared__ int part[1024];
    int tid = threadIdx.x;
    int per = (N + 1023) / 1024;
    int start = tid * per;
    int end = min(start + per, N);
    int s = 0;
    for (int i = start; i < end; ++i) s += deg[i];
    part[tid] = s;
    __syncthreads();
    if (tid == 0) {
        int t = 0;
        for (int i = 0; i < 1024; ++i) {
            int v = part[i];
            part[i] = t;
            t += v;
        }
    }
    __syncthreads();
    int run = part[tid];
    for (int i = start; i < end; ++i) {
        row_start[i] = run;
        run += deg[i];
    }
    if (tid == 1023) row_start[N] = run;
}

__global__ __launch_bounds__(256) void scatter_kernel(
    const int* __restrict__ src, const int* __restrict__ dst,
    const int* __restrict__ row_start, int* __restrict__ cursor,
    int2* __restrict__ csr, int E) {
    int i = blockIdx.x * blockDim.x + threadIdx.x;
    int stride = gridDim.x * blockDim.x;
    for (; i < E; i += stride) {
        int v = dst[i];
        int p = row_start[v] + atomicAdd(&cursor[v], 1);
        csr[p] = make_int2(i, src[i]);
    }
}

// ---------------- Weight prep ----------------
__device__ __forceinline__ void wsplit(const float* W, ushort* Wth, ushort* Wtl,
                                       int K, int N, int t) {
    int k = t / N, n = t - k * N;
    float v = W[t];
    ushort hv = f2bf_rne(v);
    float hf = bf2f(hv);
    ushort lv = f2bf_rne(v - hf);
    Wth[(size_t)n * K + k] = hv;
    Wtl[(size_t)n * K + k] = lv;
}

__global__ __launch_bounds__(256) void prep_all(
    const float* W11, ushort* W11h, ushort* W11l,
    const float* W12, ushort* W12h, ushort* W12l,
    const float* W21, ushort* W21h, ushort* W21l,
    const float* W22, ushort* W22h, ushort* W22l,
    const float* W31, ushort* W31h, ushort* W31l,
    const float* W32, ushort* W32h, ushort* W32l) {
    int t = blockIdx.x * blockDim.x + threadIdx.x;
    const int s1 = 128 * 256, s2 = s1 + 256 * 256, s3 = s2 + 256 * 128;
    const int s4 = s3 + 128 * 128, s5 = s4 + 128 * 64, s6 = s5 + 64 * 64;
    if (t < s1) wsplit(W11, W11h, W11l, 128, 256, t);
    else if (t < s2) wsplit(W12, W12h, W12l, 256, 256, t - s1);
    else if (t < s3) wsplit(W21, W21h, W21l, 256, 128, t - s2);
    else if (t < s4) wsplit(W22, W22h, W22l, 128, 128, t - s3);
    else if (t < s5) wsplit(W31, W31h, W31l, 128, 64, t - s4);
    else if (t < s6) wsplit(W32, W32h, W32l, 64, 64, t - s5);
}

// ---------------- fp32 -> bf16 convert (layer-1 gather copy) --------------
__global__ __launch_bounds__(256) void f32_to_bf16(const float* __restrict__ in,
                                                   ushort* __restrict__ out, long n4) {
    long i = (long)blockIdx.x * blockDim.x + threadIdx.x;
    long stride = (long)gridDim.x * blockDim.x;
    for (; i < n4; i += stride) {
        float4 v = ((const float4*)in)[i];
        ushort4 o;
        o.x = f2bf_rne(v.x);
        o.y = f2bf_rne(v.y);
        o.z = f2bf_rne(v.z);
        o.w = f2bf_rne(v.w);
        ((ushort4*)out)[i] = o;
    }
}

// ---------------- Fused GINE aggregation ----------------
// WPN waves per node, each owning 128 channels (2/lane; We slice = 32 VGPR,
// resident). Edge meta via 2 readlanes -> SGPR; ea row via uniform float4
// loads (SMEM/broadcast, no readlane storm). CSR interleaved int2 {eid,src}.
template <int D, int WPN>
__global__ __launch_bounds__(256) void gine_agg_kernel(
    const float* __restrict__ h, const ushort* __restrict__ hb,
    const float* __restrict__ ea,
    const int* __restrict__ row_start, const int2* __restrict__ csr,
    const float* __restrict__ We, const float* __restrict__ be,
    ushort* __restrict__ uhi, ushort* __restrict__ ulo, int N) {
    constexpr int NPB = 4 / WPN;  // nodes per 256-thread block
    const int lane = threadIdx.x & 63;
    const int wid = threadIdx.x >> 6;
    const int ch0 = (wid % WPN) * 128 + lane * 2;

    float2v w[16];
#pragma unroll
    for (int k = 0; k < 16; ++k) w[k] = *(const float2v*)&We[k * D + ch0];
    const float2v bias = *(const float2v*)&be[ch0];

    int v = blockIdx.x * NPB + wid / WPN;
    const int vstride = gridDim.x * NPB;
    const float2v z2 = splat2(0.f);

    for (; v < N; v += vstride) {
        const int e0 = row_start[v];
        const int e1 = row_start[v + 1];
        float2v acc = z2;

        int i = e0;
        for (; i + 4 <= e1; i += 4) {
            int2 c2 = csr[i + (lane >> 4)];
            int eid[4], se[4];
#pragma unroll
            for (int j = 0; j < 4; ++j) {
                eid[j] = __builtin_amdgcn_readlane(c2.x, j * 16);
                se[j] = __builtin_amdgcn_readlane(c2.y, j * 16);
            }
            // issue all 4 gathers first (longest latency)
            ushort2 r[4];
#pragma unroll
            for (int j = 0; j < 4; ++j)
                r[j] = *(const ushort2*)&hb[(size_t)se[j] * D + ch0];
#pragma unroll
            for (int j = 0; j < 4; ++j) {
                const float4* ep = (const float4*)(ea + (size_t)eid[j] * 16);
                float4 ev0 = ep[0];
                float4 ev1 = ep[1];
                float4 ev2 = ep[2];
                float4 ev3 = ep[3];
                float2v p = bias;
                p = fma2(ev0.x, w[0], p);
                p = fma2(ev0.y, w[1], p);
                p = fma2(ev0.z, w[2], p);
                p = fma2(ev0.w, w[3], p);
                p = fma2(ev1.x, w[4], p);
                p = fma2(ev1.y, w[5], p);
                p = fma2(ev1.z, w[6], p);
                p = fma2(ev1.w, w[7], p);
                p = fma2(ev2.x, w[8], p);
                p = fma2(ev2.y, w[9], p);
                p = fma2(ev2.z, w[10], p);
                p = fma2(ev2.w, w[11], p);
                p = fma2(ev3.x, w[12], p);
                p = fma2(ev3.y, w[13], p);
                p = fma2(ev3.z, w[14], p);
                p = fma2(ev3.w, w[15], p);
                float2v hv;
                hv[0] = bf2f(r[j].x);
                hv[1] = bf2f(r[j].y);
                float2v m = p + hv;
                acc += __builtin_elementwise_max(m, z2);
            }
        }
        for (; i < e1; ++i) {  // tail (<=3 edges), uniform loads
            int2 ce = csr[i];
            ushort2 r = *(const ushort2*)&hb[(size_t)ce.y * D + ch0];
            const float4* ep = (const float4*)(ea + (size_t)ce.x * 16);
            float4 ev0 = ep[0];
            float4 ev1 = ep[1];
            float4 ev2 = ep[2];
            float4 ev3 = ep[3];
            float2v p = bias;
            p = fma2(ev0.x, w[0], p);
            p = fma2(ev0.y, w[1], p);
            p = fma2(ev0.z, w[2], p);
            p = fma2(ev0.w, w[3], p);
            p = fma2(ev1.x, w[4], p);
            p = fma2(ev1.y, w[5], p);
            p = fma2(ev1.z, w[6], p);
            p = fma2(ev1.w, w[7], p);
            p = fma2(ev2.x, w[8], p);
            p = fma2(ev2.y, w[9], p);
            p = fma2(ev2.z, w[10], p);
            p = fma2(ev2.w, w[11], p);
            p = fma2(ev3.x, w[12], p);
            p = fma2(ev3.y, w[13], p);
            p = fma2(ev3.z, w[14], p);
            p = fma2(ev3.w, w[15], p);
            float2v hv;
            hv[0] = bf2f(r.x);
            hv[1] = bf2f(r.y);
            float2v m = p + hv;
            acc += __builtin_elementwise_max(m, z2);
        }
        // epilogue: u = h_v + acc -> bf16 hi/lo
        float2v sv = *(const float2v*)&h[(size_t)v * D + ch0];
        float u0 = sv[0] + acc[0];
        float u1 = sv[1] + acc[1];
        ushort h0 = f2bf_rne(u0);
        ushort h1 = f2bf_rne(u1);
        ushort l0 = f2bf_rne(u0 - bf2f(h0));
        ushort l1 = f2bf_rne(u1 - bf2f(h1));
        *(ushort2*)&uhi[(size_t)v * D + ch0] = make_ushort2(h0, h1);
        *(ushort2*)&ulo[(size_t)v * D + ch0] = make_ushort2(l0, l1);
    }
}

// ---------------- Split-bf16 MFMA GEMM (+ optional fused BN stats) ---------
template <int WRITE_BF16, int STATS>
__global__ __launch_bounds__(256) void gemm_mfma(
    const ushort* __restrict__ Ah, const ushort* __restrict__ Al,
    const ushort* __restrict__ Bh, const ushort* __restrict__ Bl,
    const float* __restrict__ bias,
    float* __restrict__ Cf, ushort* __restrict__ Chi, ushort* __restrict__ Clo,
    float* __restrict__ stats, int Nreal,
    int N, int K, int relu) {
    __shared__ ushort sA[2][128][72];
    __shared__ ushort sB[2][64][72];
    const int tid = threadIdx.x;
    const int wave = tid >> 6, lane = tid & 63;
    const int lrow = lane & 15, lquad = lane >> 4;
    const int bm = blockIdx.y * 128;
    const int bn = blockIdx.x * 64;

    floatx4 acc[2][4];
#pragma unroll
    for (int i = 0; i < 2; ++i)
#pragma unroll
        for (int j = 0; j < 4; ++j) acc[i][j] = (floatx4)0.f;

    for (int k0 = 0; k0 < K; k0 += 64) {
        for (int s = tid; s < 1024; s += 256) {
            int row = s >> 3, c8 = (s & 7) * 8;
            size_t g = (size_t)(bm + row) * K + k0 + c8;
            *(int4*)&sA[0][row][c8] = *(const int4*)&Ah[g];
            *(int4*)&sA[1][row][c8] = *(const int4*)&Al[g];
        }
        for (int s = tid; s < 512; s += 256) {
            int row = s >> 3, c8 = (s & 7) * 8;
            size_t g = (size_t)(bn + row) * K + k0 + c8;
            *(int4*)&sB[0][row][c8] = *(const int4*)&Bh[g];
            *(int4*)&sB[1][row][c8] = *(const int4*)&Bl[g];
        }
        __syncthreads();
        const int rb = wave * 32;
#pragma unroll
        for (int kk = 0; kk < 2; ++kk) {
            int ko = kk * 32 + lquad * 8;
            short8 ah[2], al[2], bh[4], bl[4];
#pragma unroll
            for (int i = 0; i < 2; ++i) {
                ah[i] = *(const short8*)&sA[0][rb + i * 16 + lrow][ko];
                al[i] = *(const short8*)&sA[1][rb + i * 16 + lrow][ko];
            }
#pragma unroll
            for (int j = 0; j < 4; ++j) {
                bh[j] = *(const short8*)&sB[0][j * 16 + lrow][ko];
                bl[j] = *(const short8*)&sB[1][j * 16 + lrow][ko];
            }
#pragma unroll
            for (int i = 0; i < 2; ++i)
#pragma unroll
                for (int j = 0; j < 4; ++j) {
                    acc[i][j] = __builtin_amdgcn_mfma_f32_16x16x32_bf16(
                        ah[i], bh[j], acc[i][j], 0, 0, 0);
                    acc[i][j] = __builtin_amdgcn_mfma_f32_16x16x32_bf16(
                        ah[i], bl[j], acc[i][j], 0, 0, 0);
                    acc[i][j] = __builtin_amdgcn_mfma_f32_16x16x32_bf16(
                        al[i], bh[j], acc[i][j], 0, 0, 0);
                }
        }
        __syncthreads();
    }
    float sj[4] = {0.f, 0.f, 0.f, 0.f};
    float qj[4] = {0.f, 0.f, 0.f, 0.f};
#pragma unroll
    for (int i = 0; i < 2; ++i)
#pragma unroll
        for (int j = 0; j < 4; ++j) {
            int gc = bn + j * 16 + lrow;
            float bv = bias[gc];
#pragma unroll
            for (int r = 0; r < 4; ++r) {
                int gr = bm + wave * 32 + i * 16 + lquad * 4 + r;
                float v = acc[i][j][r] + bv;
                if (relu) v = fmaxf(v, 0.f);
                if (STATS && gr < Nreal) {
                    sj[j] += v;
                    qj[j] = fmaf(v, v, qj[j]);
                }
                if (WRITE_BF16) {
                    ushort hv = f2bf_rne(v);
                    ushort lv = f2bf_rne(v - bf2f(hv));
                    Chi[(size_t)gr * N + gc] = hv;
                    Clo[(size_t)gr * N + gc] = lv;
                } else {
                    Cf[(size_t)gr * N + gc] = v;
                }
            }
        }
    if (STATS) {
#pragma unroll
        for (int j = 0; j < 4; ++j) {
            float s = sj[j], q = qj[j];
            s += __shfl_xor(s, 16);
            s += __shfl_xor(s, 32);
            q += __shfl_xor(q, 16);
            q += __shfl_xor(q, 32);
            if (lquad == 0) {
                int gc = bn + j * 16 + lrow;
                atomicAdd(&stats[gc], s);
                atomicAdd(&stats[N + gc], q);
            }
        }
    }
}

// ---------------- BatchNorm apply (vectorized, + bf16 copy) ----------------
__global__ __launch_bounds__(256) void bn_apply_kernel(
    const float* __restrict__ r, float* __restrict__ h,
    ushort* __restrict__ hbout,
    const float* __restrict__ sums,
    const float* __restrict__ g, const float* __restrict__ bt,
    int N, int D, int Dm1) {
    int idx = blockIdx.x * blockDim.x + threadIdx.x;
    int total4 = N * D / 4;
    int stride = gridDim.x * blockDim.x;
    float invN = 1.0f / (float)N;
    for (; idx < total4; idx += stride) {
        int c = (idx * 4) & Dm1;
        float4 s4 = *(const float4*)&sums[c];
        float4 q4 = *(const float4*)&sums[D + c];
        float4 g4 = *(const float4*)&g[c];
        float4 b4 = *(const float4*)&bt[c];
        float4 r4 = ((const float4*)r)[idx];
        float4 o;
        {
            float mu = s4.x * invN;
            float var = fmaf(-mu, mu, q4.x * invN);
            o.x = (r4.x - mu) * (rsqrtf(var + 1e-5f) * g4.x) + b4.x;
            mu = s4.y * invN;
            var = fmaf(-mu, mu, q4.y * invN);
            o.y = (r4.y - mu) * (rsqrtf(var + 1e-5f) * g4.y) + b4.y;
            mu = s4.z * invN;
            var = fmaf(-mu, mu, q4.z * invN);
            o.z = (r4.z - mu) * (rsqrtf(var + 1e-5f) * g4.z) + b4.z;
            mu = s4.w * invN;
            var = fmaf(-mu, mu, q4.w * invN);
            o.w = (r4.w - mu) * (rsqrtf(var + 1e-5f) * g4.w) + b4.w;
        }
        ((float4*)h)[idx] = o;
        if (hbout) {
            ushort4 ob;
            ob.x = f2bf_rne(o.x);
            ob.y = f2bf_rne(o.y);
            ob.z = f2bf_rne(o.z);
            ob.w = f2bf_rne(o.w);
            ((ushort4*)hbout)[idx] = ob;
        }
    }
}

// ---------------- Head ----------------
__global__ void head_kernel(const float* __restrict__ h, const int* __restrict__ n_nodes,
                            const float* __restrict__ Wf1, const float* __restrict__ bf1,
                            const float* __restrict__ Wf2, const float* __restrict__ bf2,
                            float* __restrict__ out, int G) {
    int g = blockIdx.x * blockDim.x + threadIdx.x;
    if (g >= G) return;
    int s = 0;
    for (int i = 0; i <= g; ++i) s += n_nodes[i];
    const float* m = &h[(size_t)(s - 1) * 64];
    float o = bf2[0];
#pragma unroll 4
    for (int j = 0; j < 16; ++j) {
        float acc = bf1[j];
        for (int k = 0; k < 64; ++k) acc = fmaf(m[k], Wf1[k * 16 + j], acc);
        acc = fmaxf(acc, 0.f);
        o = fmaf(acc, Wf2[j], o);
    }
    out[g] = o;
}

extern "C" void kernel_launch(void* const* d_in, const int* in_sizes, int n_in,
                              void* d_out, int out_size, void* d_ws, size_t ws_size,
                              hipStream_t stream) {
    const float* x = (const float*)d_in[0];
    const float* ea = (const float*)d_in[1];
    const int* eidx = (const int*)d_in[2];
    const int* n_nodes = (const int*)d_in[3];
    const float* We1 = (const float*)d_in[4];
    const float* be1 = (const float*)d_in[5];
    const float* W11 = (const float*)d_in[6];
    const float* b11 = (const float*)d_in[7];
    const float* W12 = (const float*)d_in[8];
    const float* b12 = (const float*)d_in[9];
    const float* g1 = (const float*)d_in[10];
    const float* bt1 = (const float*)d_in[11];
    const float* We2 = (const float*)d_in[12];
    const float* be2 = (const float*)d_in[13];
    const float* W21 = (const float*)d_in[14];
    const float* b21 = (const float*)d_in[15];
    const float* W22 = (const float*)d_in[16];
    const float* b22 = (const float*)d_in[17];
    const float* g2 = (const float*)d_in[18];
    const float* bt2 = (const float*)d_in[19];
    const float* We3 = (const float*)d_in[20];
    const float* be3 = (const float*)d_in[21];
    const float* W31 = (const float*)d_in[22];
    const float* b31 = (const float*)d_in[23];
    const float* W32 = (const float*)d_in[24];
    const float* b32 = (const float*)d_in[25];
    const float* g3 = (const float*)d_in[26];
    const float* bt3 = (const float*)d_in[27];
    const float* Wf1 = (const float*)d_in[28];
    const float* bf1 = (const float*)d_in[29];
    const float* Wf2 = (const float*)d_in[30];
    const float* bf2 = (const float*)d_in[31];

    const int N = in_sizes[0] / 128;  // 50000
    const int E = in_sizes[2] / 2;    // 800000
    const int G = in_sizes[3];        // 500
    const int Mp = ((N + 127) / 128) * 128;  // 50048
    const int* srcp = eidx;
    const int* dstp = eidx + E;

    float* H = (float*)d_ws;            // Mp x 256 fp32
    float* UR = H + (size_t)Mp * 256;   // Mp x 256: u(hi/lo bf16) / r(fp32)
    float* TT = UR + (size_t)Mp * 256;  // Mp x 256: t(hi/lo bf16) / hb(bf16)
    float* stats1 = TT + (size_t)Mp * 256;  // 512
    float* stats2 = stats1 + 512;           // 256
    float* stats3 = stats2 + 256;           // 128
    int* deg = (int*)(stats3 + 128);        // N
    int* cursor = deg + N;                  // N
    int* row_start = cursor + N;            // N+1 (+1 pad for int2 align)
    int2* csr = (int2*)(row_start + N + 2); // E int2
    size_t woff = (size_t)((int*)(csr + E) - (int*)d_ws);
    woff = (woff + 3) & ~(size_t)3;
    ushort* wp = (ushort*)((int*)d_ws + woff);
    ushort* W11th = wp; wp += 128 * 256;
    ushort* W11tl = wp; wp += 128 * 256;
    ushort* W12th = wp; wp += 256 * 256;
    ushort* W12tl = wp; wp += 256 * 256;
    ushort* W21th = wp; wp += 256 * 128;
    ushort* W21tl = wp; wp += 256 * 128;
    ushort* W22th = wp; wp += 128 * 128;
    ushort* W22tl = wp; wp += 128 * 128;
    ushort* W31th = wp; wp += 128 * 64;
    ushort* W31tl = wp; wp += 128 * 64;
    ushort* W32th = wp; wp += 64 * 64;
    ushort* W32tl = wp; wp += 64 * 64;

    hipMemsetAsync(stats1, 0, 896 * sizeof(float) + (size_t)2 * N * sizeof(int), stream);

    const int prepTot = 128 * 256 + 256 * 256 + 256 * 128 + 128 * 128 + 128 * 64 + 64 * 64;
    prep_all<<<(prepTot + 255) / 256, 256, 0, stream>>>(
        W11, W11th, W11tl, W12, W12th, W12tl, W21, W21th, W21tl,
        W22, W22th, W22tl, W31, W31th, W31tl, W32, W32th, W32tl);

    hist_kernel<<<3125, 256, 0, stream>>>(dstp, deg, E);
    scan_kernel<<<1, 1024, 0, stream>>>(deg, row_start, N);
    scatter_kernel<<<3125, 256, 0, stream>>>(srcp, dstp, row_start, cursor, csr, E);

    const int gy = Mp / 128;
    float* R = UR;
    ushort* HB = (ushort*)TT;  // bf16 gather copy lives in the (dead) TT region

    // ---------------- Layer 1: 128 -> 256 -> 256 ----------------
    {
        ushort* Uhi = (ushort*)UR; ushort* Ulo = Uhi + (size_t)Mp * 128;
        ushort* Thi = (ushort*)TT; ushort* Tlo = Thi + (size_t)Mp * 256;
        f32_to_bf16<<<2048, 256, 0, stream>>>(x, HB, (long)N * 128 / 4);
        gine_agg_kernel<128, 1><<<(N + 3) / 4, 256, 0, stream>>>(
            x, HB, ea, row_start, csr, We1, be1, Uhi, Ulo, N);
        gemm_mfma<1, 0><<<dim3(4, gy), 256, 0, stream>>>(
            Uhi, Ulo, W11th, W11tl, b11, nullptr, Thi, Tlo, nullptr, 0, 256, 128, 1);
        gemm_mfma<0, 1><<<dim3(4, gy), 256, 0, stream>>>(
            Thi, Tlo, W12th, W12tl, b12, R, nullptr, nullptr, stats1, N, 256, 256, 1);
        bn_apply_kernel<<<2048, 256, 0, stream>>>(R, H, HB, stats1, g1, bt1, N, 256, 255);
    }

    // ---------------- Layer 2: 256 -> 128 -> 128 ----------------
    {
        ushort* Uhi = (ushort*)UR; ushort* Ulo = Uhi + (size_t)Mp * 256;
        ushort* Thi = (ushort*)TT; ushort* Tlo = Thi + (size_t)Mp * 128;
        gine_agg_kernel<256, 2><<<(N + 1) / 2, 256, 0, stream>>>(
            H, HB, ea, row_start, csr, We2, be2, Uhi, Ulo, N);
        gemm_mfma<1, 0><<<dim3(2, gy), 256, 0, stream>>>(
            Uhi, Ulo, W21th, W21tl, b21, nullptr, Thi, Tlo, nullptr, 0, 128, 256, 1);
        gemm_mfma<0, 1><<<dim3(2, gy), 256, 0, stream>>>(
            Thi, Tlo, W22th, W22tl, b22, R, nullptr, nullptr, stats2, N, 128, 128, 1);
        bn_apply_kernel<<<2048, 256, 0, stream>>>(R, H, HB, stats2, g2, bt2, N, 128, 127);
    }

    // ---------------- Layer 3: 128 -> 64 -> 64 ----------------
    {
        ushort* Uhi = (ushort*)UR; ushort* Ulo = Uhi + (size_t)Mp * 128;
        ushort* Thi = (ushort*)TT; ushort* Tlo = Thi + (size_t)Mp * 64;
        gine_agg_kernel<128, 1><<<(N + 3) / 4, 256, 0, stream>>>(
            H, HB, ea, row_start, csr, We3, be3, Uhi, Ulo, N);
        gemm_mfma<1, 0><<<dim3(1, gy), 256, 0, stream>>>(
            Uhi, Ulo, W31th, W31tl, b31, nullptr, Thi, Tlo, nullptr, 0, 64, 128, 1);
        gemm_mfma<0, 1><<<dim3(1, gy), 256, 0, stream>>>(
            Thi, Tlo, W32th, W32tl, b32, R, nullptr, nullptr, stats3, N, 64, 64, 1);
        bn_apply_kernel<<<2048, 256, 0, stream>>>(R, H, nullptr, stats3, g3, bt3, N, 64, 63);
    }

    // ---------------- Head ----------------
    head_kernel<<<(G + 255) / 256, 256, 0, stream>>>(H, n_nodes, Wf1, bf1, Wf2, bf2,
                                                     (float*)d_out, G);
}